// Round 1
// baseline (1415.395 us; speedup 1.0000x reference)
//
#include <hip/hip_runtime.h>
#include <math.h>

#define T_STEPS 16
#define DIM_X 64
#define DIM_H 128
#define DIM_K 192   // DIM_X + DIM_H
#define G4H 512     // 4*DIM_H
#define GSEQ 32     // sequences per block
#define NTHREADS 512

__device__ __forceinline__ float fsigmoid(float x) {
    return 1.0f / (1.0f + __expf(-x));
}
__device__ __forceinline__ float ftanh_(float x) {
    float a = fabsf(x);
    float e = __expf(2.0f * a);
    float r = 1.0f - 2.0f / (e + 1.0f);   // safe at e=inf -> r=1
    return copysignf(r, x);
}

// Pack W into k-chunk-major float4 layout: Wq[kc][row][4] = Wcat[row][4kc..4kc+3]
// where Wcat[row] = [W_ih row (64) | W_hh row (128)]. Also bsum = b_ih + b_hh.
__global__ void pack_weights(const float* __restrict__ W_ih, const float* __restrict__ W_hh,
                             const float* __restrict__ b_ih, const float* __restrict__ b_hh,
                             float* __restrict__ Wq, float* __restrict__ bsum) {
    int i = blockIdx.x * blockDim.x + threadIdx.x;
    if (i < G4H * DIM_K) {
        int row = i / DIM_K;
        int k = i % DIM_K;
        float v = (k < DIM_X) ? W_ih[row * DIM_X + k] : W_hh[row * DIM_H + (k - DIM_X)];
        int kc = k >> 2, j = k & 3;
        Wq[(kc * G4H + row) * 4 + j] = v;
    }
    if (i < G4H) bsum[i] = b_ih[i] + b_hh[i];
}

__global__ void zero_meta(int* __restrict__ p, int n) {
    int i = blockIdx.x * blockDim.x + threadIdx.x;
    if (i < n) p[i] = 0;
}

__global__ void count_lens(const int* __restrict__ xn, int N, int* __restrict__ counts) {
    int i = blockIdx.x * blockDim.x + threadIdx.x;
    if (i < N) {
        int len = xn[i * 4 + 3];
        len = min(max(len, 1), T_STEPS);
        atomicAdd(&counts[len - 1], 1);
    }
}

__global__ void scan_offsets(const int* __restrict__ counts, int* __restrict__ offsets) {
    if (blockIdx.x == 0 && threadIdx.x == 0) {
        int acc = 0;
        for (int i = 0; i < T_STEPS; ++i) { offsets[i] = acc; acc += counts[i]; }
    }
}

__global__ void scatter_seq(const int* __restrict__ xn, int N, const int* __restrict__ offsets,
                            int* __restrict__ cursors, int* __restrict__ list) {
    int i = blockIdx.x * blockDim.x + threadIdx.x;
    if (i < N) {
        int len = xn[i * 4 + 3];
        len = min(max(len, 1), T_STEPS);
        int pos = atomicAdd(&cursors[len - 1], 1);
        list[offsets[len - 1] + pos] = i;
    }
}

// Block: 512 threads = 128 units x 4 seq-groups; 32 sequences/block (8 per group).
// Thread (u, sg) computes gate rows {u, u+128, u+256, u+384} for its 8 sequences.
// [x_t ; h] staged in LDS per sequence (192 floats); LDS reads are wave-broadcast.
__global__ __launch_bounds__(NTHREADS, 2)
void lstm_main(const float* __restrict__ xw, const int* __restrict__ xn,
               const float* __restrict__ Wq, const float* __restrict__ bsum,
               const int* __restrict__ list, int N, float* __restrict__ out)
{
    __shared__ float xh[GSEQ][DIM_K];
    __shared__ int s_seq[GSEQ];
    __shared__ int s_len[GSEQ];
    __shared__ int s_maxlen;

    const int tid = threadIdx.x;
    const int u = tid & (DIM_H - 1);
    const int sg = tid >> 7;
    const int sbase = sg * 8;

    if (tid == 0) s_maxlen = 0;
    __syncthreads();
    if (tid < GSEQ) {
        int idx = blockIdx.x * GSEQ + tid;
        int seq = (idx < N) ? list[idx] : -1;
        s_seq[tid] = seq;
        int len = 0;
        if (seq >= 0) {
            len = xn[seq * 4 + 3];
            len = min(max(len, 1), T_STEPS);
        }
        s_len[tid] = len;
        atomicMax(&s_maxlen, len);
    }
#pragma unroll
    for (int j = 0; j < 8; ++j) xh[sbase + j][DIM_X + u] = 0.0f;
    __syncthreads();
    const int maxlen = s_maxlen;

    const float bi = bsum[u];
    const float bf = bsum[u + 128];
    const float bg = bsum[u + 256];
    const float bo = bsum[u + 384];

    float c[8], h[8];
#pragma unroll
    for (int j = 0; j < 8; ++j) { c[j] = 0.0f; h[j] = 0.0f; }

    // x-staging role: 16 threads per sequence, float4 each
    const int xs = tid >> 4;
    const int xp = (tid & 15) << 2;

    for (int t = 0; t < maxlen; ++t) {
        {
            int seq = s_seq[xs];
            if (seq >= 0) {
                const float4 xv = *reinterpret_cast<const float4*>(
                    xw + ((size_t)seq * T_STEPS + t) * DIM_X + xp);
                *reinterpret_cast<float4*>(&xh[xs][xp]) = xv;
            }
        }
        __syncthreads();   // x_t + h(t-1) visible to all

        float acc[8][4];
#pragma unroll
        for (int j = 0; j < 8; ++j) {
            acc[j][0] = bi; acc[j][1] = bf; acc[j][2] = bg; acc[j][3] = bo;
        }

        for (int kc = 0; kc < DIM_K / 4; ++kc) {
            const float4* wrow = reinterpret_cast<const float4*>(Wq + kc * (G4H * 4));
            float4 wi = wrow[u];
            float4 wf = wrow[u + 128];
            float4 wg = wrow[u + 256];
            float4 wo = wrow[u + 384];
#pragma unroll
            for (int j = 0; j < 8; ++j) {
                float4 hv = *reinterpret_cast<const float4*>(&xh[sbase + j][kc << 2]);
                acc[j][0] += hv.x * wi.x; acc[j][0] += hv.y * wi.y;
                acc[j][0] += hv.z * wi.z; acc[j][0] += hv.w * wi.w;
                acc[j][1] += hv.x * wf.x; acc[j][1] += hv.y * wf.y;
                acc[j][1] += hv.z * wf.z; acc[j][1] += hv.w * wf.w;
                acc[j][2] += hv.x * wg.x; acc[j][2] += hv.y * wg.y;
                acc[j][2] += hv.z * wg.z; acc[j][2] += hv.w * wg.w;
                acc[j][3] += hv.x * wo.x; acc[j][3] += hv.y * wo.y;
                acc[j][3] += hv.z * wo.z; acc[j][3] += hv.w * wo.w;
            }
        }

        __syncthreads();   // all xh reads of this step done before h overwrite

#pragma unroll
        for (int j = 0; j < 8; ++j) {
            float ig = fsigmoid(acc[j][0]);
            float fg = fsigmoid(acc[j][1]);
            float gg = ftanh_(acc[j][2]);
            float og = fsigmoid(acc[j][3]);
            c[j] = fg * c[j] + ig * gg;
            h[j] = og * ftanh_(c[j]);
            int s = sbase + j;
            xh[s][DIM_X + u] = h[j];
            if (t == s_len[s] - 1) {
                int sq = s_seq[s];
                if (sq >= 0) out[(size_t)sq * DIM_H + u] = h[j];
            }
        }
    }
}

extern "C" void kernel_launch(void* const* d_in, const int* in_sizes, int n_in,
                              void* d_out, int out_size, void* d_ws, size_t ws_size,
                              hipStream_t stream) {
    const float* xw   = (const float*)d_in[0];
    const int*   xn   = (const int*)d_in[1];
    const float* W_ih = (const float*)d_in[2];
    const float* W_hh = (const float*)d_in[3];
    const float* b_ih = (const float*)d_in[4];
    const float* b_hh = (const float*)d_in[5];
    float* out = (float*)d_out;

    const int N = in_sizes[0] / (T_STEPS * DIM_X);   // bs*sl

    // workspace layout
    char* ws = (char*)d_ws;
    float* Wq      = (float*)ws;                         // 512*192*4 = 393216 B
    float* bsum    = (float*)(ws + 393216);              // 2048 B
    int*   counts  = (int*)(ws + 395264);                // 16 ints
    int*   offsets = (int*)(ws + 395328);                // 16 ints
    int*   cursors = (int*)(ws + 395392);                // 16 ints
    int*   list    = (int*)(ws + 395456);                // N ints

    zero_meta<<<1, 64, 0, stream>>>(counts, 48);
    pack_weights<<<(G4H * DIM_K + 255) / 256, 256, 0, stream>>>(W_ih, W_hh, b_ih, b_hh, Wq, bsum);
    count_lens<<<(N + 255) / 256, 256, 0, stream>>>(xn, N, counts);
    scan_offsets<<<1, 1, 0, stream>>>(counts, offsets);
    scatter_seq<<<(N + 255) / 256, 256, 0, stream>>>(xn, N, offsets, cursors, list);

    const int nblocks = (N + GSEQ - 1) / GSEQ;
    lstm_main<<<nblocks, NTHREADS, 0, stream>>>(xw, xn, Wq, bsum, list, N, out);
}

// Round 6
// 505.068 us; speedup vs baseline: 2.8024x; 2.8024x over previous
//
#include <hip/hip_runtime.h>
#include <math.h>

#define T_STEPS 16
#define DIM_X 64
#define DIM_H 128
#define DIM_K 192
#define NPACK 512        // packed gate rows = 4*DIM_H
#define MSEQ 64          // sequences per block
#define NTHREADS 512     // 8 waves
#define LDK 200          // padded LDS row length in ushorts (400B, 16B-aligned, conflict-free)

typedef __attribute__((ext_vector_type(8))) short bf16x8;
typedef __attribute__((ext_vector_type(4))) float f32x4;

__device__ __forceinline__ float fsigmoid(float x) {
    return 1.0f / (1.0f + __expf(-x));
}
__device__ __forceinline__ float ftanh_(float x) {
    float a = fabsf(x);
    float e = __expf(2.0f * a);
    float r = 1.0f - 2.0f / (e + 1.0f);   // safe at e=inf -> r=1
    return copysignf(r, x);
}
__device__ __forceinline__ unsigned short bf16_rn(float x) {
    unsigned int b = __float_as_uint(x);
    b += 0x7FFFu + ((b >> 16) & 1u);
    return (unsigned short)(b >> 16);
}
__device__ __forceinline__ float bf16_to_f(unsigned short u) {
    return __uint_as_float(((unsigned int)u) << 16);
}

// Pack W rows gate-major per 16-unit block: packed row p -> ub=p>>6, g=(p>>4)&3, u''=p&15,
// orig gate row r = g*128 + ub*16 + u''. Row-major [p][k] over k = [x(64) | h(128)].
// Split each weight into bf16 hi + bf16 lo (hi+lo ~ fp32-exact to 2^-18).
__global__ void pack_weights(const float* __restrict__ W_ih, const float* __restrict__ W_hh,
                             const float* __restrict__ b_ih, const float* __restrict__ b_hh,
                             unsigned short* __restrict__ Whi, unsigned short* __restrict__ Wlo,
                             float* __restrict__ bsum) {
    int i = blockIdx.x * blockDim.x + threadIdx.x;
    if (i >= NPACK * DIM_K) return;
    int p = i / DIM_K, k = i % DIM_K;
    int g = (p >> 4) & 3;
    int unit = ((p >> 6) << 4) + (p & 15);
    int r = g * DIM_H + unit;
    float v = (k < DIM_X) ? W_ih[r * DIM_X + k] : W_hh[r * DIM_H + (k - DIM_X)];
    unsigned short hi = bf16_rn(v);
    Whi[i] = hi;
    Wlo[i] = bf16_rn(v - bf16_to_f(hi));
    if (k == 0) bsum[p] = b_ih[r] + b_hh[r];
}

// Single-block binning: histogram by length, DESCENDING offsets (longest first), scatter.
__global__ void bin_seqs(const int* __restrict__ xn, int N, int* __restrict__ list) {
    __shared__ int hist[T_STEPS], offs[T_STEPS], cur[T_STEPS];
    int tid = threadIdx.x;
    if (tid < T_STEPS) hist[tid] = 0;
    __syncthreads();
    for (int i = tid; i < N; i += blockDim.x) {
        int len = xn[i * 4 + 3];
        len = min(max(len, 1), T_STEPS);
        atomicAdd(&hist[len - 1], 1);
    }
    __syncthreads();
    if (tid == 0) {
        int acc = 0;
        for (int b = T_STEPS - 1; b >= 0; --b) { offs[b] = acc; acc += hist[b]; }
    }
    __syncthreads();
    if (tid < T_STEPS) cur[tid] = offs[tid];
    __syncthreads();
    for (int i = tid; i < N; i += blockDim.x) {
        int len = xn[i * 4 + 3];
        len = min(max(len, 1), T_STEPS);
        int pos = atomicAdd(&cur[len - 1], 1);
        list[pos] = i;
    }
}

// 8 waves x 64 seqs. Wave w owns packed rows [w*64, w*64+64) = units [w*16,(w+1)*16) x 4 gates.
// mfma_f32_16x16x32_bf16: A[m][k]: lane holds row (l&15), k-octet (l>>4)*8.
//                         B[k][n]: lane holds col (l&15), k-octet (l>>4)*8 (row-major [n][k] load).
//                         D[m][n]: lane holds n=(l&15), m=(l>>4)*4+reg  [m89 verified].
// => lane's unit = w*16 + (l&15) for all 4 gate-tiles; seqs = m*16 + (l>>4)*4 + j. Lane-local LSTM cell.
__global__ __launch_bounds__(NTHREADS)
void lstm_main(const float* __restrict__ xw, const int* __restrict__ xn,
               const unsigned short* __restrict__ Whi, const unsigned short* __restrict__ Wlo,
               const float* __restrict__ bsum, const int* __restrict__ list,
               int N, float* __restrict__ out)
{
    __shared__ unsigned short xh_hi[MSEQ][LDK];
    __shared__ unsigned short xh_lo[MSEQ][LDK];
    __shared__ int s_seq[MSEQ];
    __shared__ int s_len[MSEQ];
    __shared__ int s_maxlen;

    const int tid = threadIdx.x;
    const int wv = tid >> 6;
    const int lane = tid & 63;
    const int lr = lane & 15;
    const int lh = lane >> 4;
    const int unit = (wv << 4) + lr;

    if (tid == 0) s_maxlen = 0;
    __syncthreads();
    if (tid < MSEQ) {
        int idx = blockIdx.x * MSEQ + tid;
        int seq = (idx < N) ? list[idx] : -1;
        s_seq[tid] = seq;
        int len = 0;
        if (seq >= 0) { len = xn[seq * 4 + 3]; len = min(max(len, 1), T_STEPS); }
        s_len[tid] = len;
        atomicMax(&s_maxlen, len);
    }
    // zero h region (k = 64..191): each thread covers its 16 (seq, unit) slots
#pragma unroll
    for (int m = 0; m < 4; ++m)
#pragma unroll
        for (int j = 0; j < 4; ++j) {
            int s = (m << 4) + (lh << 2) + j;
            xh_hi[s][DIM_X + unit] = 0;
            xh_lo[s][DIM_X + unit] = 0;
        }
    __syncthreads();
    const int maxlen = s_maxlen;

    // per-lane constants
    float bias[4];
#pragma unroll
    for (int g = 0; g < 4; ++g) bias[g] = bsum[(wv << 6) + (g << 4) + lr];

    int lenv[4][4];
#pragma unroll
    for (int m = 0; m < 4; ++m)
#pragma unroll
        for (int j = 0; j < 4; ++j) lenv[m][j] = s_len[(m << 4) + (lh << 2) + j];

    float c[4][4];
#pragma unroll
    for (int m = 0; m < 4; ++m)
#pragma unroll
        for (int j = 0; j < 4; ++j) c[m][j] = 0.0f;

    // x staging role: thread -> (seq tid>>3, k-octet (tid&7)*8)
    const int xsl = tid >> 3;
    const int xko = (tid & 7) << 3;
    const long xseq = (long)max(s_seq[xsl], 0);

    // stage x(0)
    {
        const float* xp = xw + ((size_t)xseq * T_STEPS + 0) * DIM_X + xko;
        float4 a = *(const float4*)xp;
        float4 b = *(const float4*)(xp + 4);
        float xv[8] = {a.x, a.y, a.z, a.w, b.x, b.y, b.z, b.w};
        bf16x8 hv, lv;
#pragma unroll
        for (int e = 0; e < 8; ++e) {
            unsigned short h = bf16_rn(xv[e]);
            hv[e] = (short)h;
            lv[e] = (short)bf16_rn(xv[e] - bf16_to_f(h));
        }
        *(bf16x8*)&xh_hi[xsl][xko] = hv;
        *(bf16x8*)&xh_lo[xsl][xko] = lv;
    }

    const unsigned short* __restrict__ wbase_h = Whi + (size_t)(wv << 6) * DIM_K + (lh << 3);
    const unsigned short* __restrict__ wbase_l = Wlo + (size_t)(wv << 6) * DIM_K + (lh << 3);

    for (int t = 0; t < maxlen; ++t) {
        __syncthreads();   // x(t) + h(t-1) staged

        f32x4 acc[4][4];
#pragma unroll
        for (int m = 0; m < 4; ++m)
#pragma unroll
            for (int g = 0; g < 4; ++g)
                acc[m][g] = (f32x4){bias[g], bias[g], bias[g], bias[g]};

        for (int kc = 0; kc < 6; ++kc) {
            const int kb = kc << 5;           // k base (elements)
            bf16x8 ahi[4], alo[4];
#pragma unroll
            for (int m = 0; m < 4; ++m) {
                ahi[m] = *(const bf16x8*)&xh_hi[(m << 4) + lr][kb + (lh << 3)];
                alo[m] = *(const bf16x8*)&xh_lo[(m << 4) + lr][kb + (lh << 3)];
            }
            bf16x8 bhi[4], blo[4];
#pragma unroll
            for (int g = 0; g < 4; ++g) {
                const size_t off = (size_t)((g << 4) + lr) * DIM_K + kb;
                bhi[g] = *(const bf16x8*)(wbase_h + off);
                blo[g] = *(const bf16x8*)(wbase_l + off);
            }
#pragma unroll
            for (int m = 0; m < 4; ++m)
#pragma unroll
                for (int g = 0; g < 4; ++g) {
                    acc[m][g] = __builtin_amdgcn_mfma_f32_16x16x32_bf16(ahi[m], bhi[g], acc[m][g], 0, 0, 0);
                    acc[m][g] = __builtin_amdgcn_mfma_f32_16x16x32_bf16(alo[m], bhi[g], acc[m][g], 0, 0, 0);
                    acc[m][g] = __builtin_amdgcn_mfma_f32_16x16x32_bf16(ahi[m], blo[g], acc[m][g], 0, 0, 0);
                }
        }

        // prefetch x(t+1) into registers (hide HBM/L2 latency under epilogue)
        const bool do_x = (t + 1 < maxlen);
        float4 xa, xb;
        if (do_x) {
            const float* xp = xw + ((size_t)xseq * T_STEPS + (t + 1)) * DIM_X + xko;
            xa = *(const float4*)xp;
            xb = *(const float4*)(xp + 4);
        }

        __syncthreads();   // all LDS reads of step t done

        if (do_x) {
            float xv[8] = {xa.x, xa.y, xa.z, xa.w, xb.x, xb.y, xb.z, xb.w};
            bf16x8 hv, lv;
#pragma unroll
            for (int e = 0; e < 8; ++e) {
                unsigned short h = bf16_rn(xv[e]);
                hv[e] = (short)h;
                lv[e] = (short)bf16_rn(xv[e] - bf16_to_f(h));
            }
            *(bf16x8*)&xh_hi[xsl][xko] = hv;
            *(bf16x8*)&xh_lo[xsl][xko] = lv;
        }

#pragma unroll
        for (int m = 0; m < 4; ++m)
#pragma unroll
            for (int j = 0; j < 4; ++j) {
                float iv = fsigmoid(acc[m][0][j]);
                float fv = fsigmoid(acc[m][1][j]);
                float gv = ftanh_(acc[m][2][j]);
                float ov = fsigmoid(acc[m][3][j]);
                float cv = fv * c[m][j] + iv * gv;
                c[m][j] = cv;
                float hv = ov * ftanh_(cv);
                int s = (m << 4) + (lh << 2) + j;
                unsigned short hh = bf16_rn(hv);
                xh_hi[s][DIM_X + unit] = hh;
                xh_lo[s][DIM_X + unit] = bf16_rn(hv - bf16_to_f(hh));
                if (t == lenv[m][j] - 1) {
                    int gs = s_seq[s];
                    if (gs >= 0) out[(size_t)gs * DIM_H + unit] = hv;
                }
            }
    }
}

extern "C" void kernel_launch(void* const* d_in, const int* in_sizes, int n_in,
                              void* d_out, int out_size, void* d_ws, size_t ws_size,
                              hipStream_t stream) {
    const float* xw   = (const float*)d_in[0];
    const int*   xn   = (const int*)d_in[1];
    const float* W_ih = (const float*)d_in[2];
    const float* W_hh = (const float*)d_in[3];
    const float* b_ih = (const float*)d_in[4];
    const float* b_hh = (const float*)d_in[5];
    float* out = (float*)d_out;

    const int N = in_sizes[0] / (T_STEPS * DIM_X);   // bs*sl

    char* ws = (char*)d_ws;
    unsigned short* Whi = (unsigned short*)ws;                 // 512*192*2 = 196608 B
    unsigned short* Wlo = (unsigned short*)(ws + 196608);      // 196608 B
    float*          bsum = (float*)(ws + 393216);              // 2048 B
    int*            list = (int*)(ws + 395264);                // N*4 B

    pack_weights<<<(NPACK * DIM_K + 255) / 256, 256, 0, stream>>>(W_ih, W_hh, b_ih, b_hh, Whi, Wlo, bsum);
    bin_seqs<<<1, 1024, 0, stream>>>(xn, N, list);

    const int nblocks = (N + MSEQ - 1) / MSEQ;
    lstm_main<<<nblocks, NTHREADS, 0, stream>>>(xw, xn, Whi, Wlo, bsum, list, N, out);
}